// Round 7
// baseline (668.215 us; speedup 1.0000x reference)
//
#include <hip/hip_runtime.h>

// LinkPredictor: score[e] = w2 . relu(W1 . concat(h[src[e]], h[dst[e]]) + b1) + b2
// N_NODES=100000, N_EDGES=1600000, D=128, HIDDEN=256
//
// R7: (a) u_gemm loads B-frags from precvt bf16 W1 — fp32 frag loads had ~4x
// cache-line amplification (32B-strided x/y pairs re-touching lines) ≈ 110 us
// of the 150 us. (b) edges counting-sorted by src; one 16-lane group per node
// holds us in regs across its run -> removes half the random gather lines
// (per-CU line-in-flight cap ~100 is the edge-pass bottleneck, R5 vs R6).

#define NNODES 100000
#define E_TOTAL 1600000
#define D 128
#define K2 256
#define H 256

typedef short bf16x8 __attribute__((ext_vector_type(8)));
typedef short bf16x4 __attribute__((ext_vector_type(4)));
typedef float f32x4 __attribute__((ext_vector_type(4)));
typedef const __attribute__((address_space(1))) unsigned short* gas_t;
typedef __attribute__((address_space(3))) unsigned short* las_t;

__device__ __forceinline__ unsigned short f2bf(float f) {
    unsigned u = __float_as_uint(f);
    u += 0x7fff + ((u >> 16) & 1);   // round-to-nearest-even
    return (unsigned short)(u >> 16);
}
__device__ __forceinline__ float bf2f(unsigned short s) {
    return __uint_as_float((unsigned)s << 16);
}

// ---------------- cvt W1 -> bf16 (128 KB, one-shot) ----------------
__global__ void cvt_w1(const float* __restrict__ W1, unsigned short* __restrict__ w1bf, int n4) {
    int i = blockIdx.x * blockDim.x + threadIdx.x;
    if (i >= n4) return;
    float4 v = ((const float4*)W1)[i];
    ushort4 o;
    o.x = f2bf(v.x); o.y = f2bf(v.y); o.z = f2bf(v.z); o.w = f2bf(v.w);
    ((ushort4*)w1bf)[i] = o;
}

// ---------------- u_gemm: per-node projections Us/Ud ----------------
// R6 body; only change: B fragments now bf16x8 loads from w1bf (perfect
// 64B-line coverage per row: quads contiguous).
__global__ __launch_bounds__(256, 2) void u_gemm(
    const float* __restrict__ h,
    const unsigned short* __restrict__ w1bf,
    const float* __restrict__ b1,
    unsigned short* __restrict__ Us,
    unsigned short* __restrict__ Ud)
{
    __shared__ __align__(16) unsigned short A[64 * 136];   // 17408 B
    __shared__ __align__(16) unsigned short S[64 * 268];   // 34304 B

    const int tid = threadIdx.x;
    const int wave = tid >> 6;
    const int lane = tid & 63;
    const int l15 = lane & 15;
    const int quad = lane >> 4;

    const int r0 = blockIdx.x * 64;
    int rows = NNODES - r0; if (rows > 64) rows = 64;

    const float4* hf4 = (const float4*)(h + (size_t)r0 * D);
    const int lim = rows * 32;
#pragma unroll
    for (int i = 0; i < 8; ++i) {
        int j = tid + i * 256;
        if (j < lim) {
            float4 v = hf4[j];
            bf16x4 b;
            b[0] = (short)f2bf(v.x); b[1] = (short)f2bf(v.y);
            b[2] = (short)f2bf(v.z); b[3] = (short)f2bf(v.w);
            *(bf16x4*)&A[(j >> 5) * 136 + (j & 31) * 4] = b;
        }
    }
    __syncthreads();

    for (int half = 0; half < 2; ++half) {
        const int koff = half * 128;
        unsigned short* U = half ? Ud : Us;

        bf16x8 B[4][4];
        float bias[4];
#pragma unroll
        for (int nt = 0; nt < 4; ++nt) {
            const int n = wave * 64 + nt * 16 + l15;
            bias[nt] = half ? 0.f : b1[n];
#pragma unroll
            for (int kit = 0; kit < 4; ++kit)
                B[kit][nt] = *(const bf16x8*)(w1bf + (size_t)n * K2 + koff + kit * 32 + quad * 8);
        }

        f32x4 acc[4][4];
        const f32x4 zero = {0.f, 0.f, 0.f, 0.f};
#pragma unroll
        for (int ms = 0; ms < 4; ++ms)
#pragma unroll
            for (int nt = 0; nt < 4; ++nt)
                acc[ms][nt] = zero;

#pragma unroll
        for (int kit = 0; kit < 4; ++kit) {
            bf16x8 a[4];
#pragma unroll
            for (int ms = 0; ms < 4; ++ms)
                a[ms] = *(const bf16x8*)&A[(ms * 16 + l15) * 136 + kit * 32 + quad * 8];
#pragma unroll
            for (int ms = 0; ms < 4; ++ms)
#pragma unroll
                for (int nt = 0; nt < 4; ++nt)
                    acc[ms][nt] = __builtin_amdgcn_mfma_f32_16x16x32_bf16(
                        a[ms], B[kit][nt], acc[ms][nt], 0, 0, 0);
        }

        if (half) __syncthreads();
#pragma unroll
        for (int ms = 0; ms < 4; ++ms)
#pragma unroll
            for (int r = 0; r < 4; ++r) {
                const int m = ms * 16 + quad * 4 + r;
#pragma unroll
                for (int nt = 0; nt < 4; ++nt)
                    S[m * 268 + wave * 64 + nt * 16 + l15] =
                        f2bf(acc[ms][nt][r] + bias[nt]);
            }
        __syncthreads();

#pragma unroll
        for (int i = 0; i < 8; ++i) {
            const int j = i * 256 + tid;
            const int row = j >> 5;
            const int cc = j & 31;
            if (row < rows) {
                bf16x8 vv = *(const bf16x8*)&S[row * 268 + cc * 8];
                *(bf16x8*)(U + (size_t)(r0 + row) * H + cc * 8) = vv;
            }
        }
    }
}

// ---------------- counting sort by src ----------------
__global__ void hist_kernel(const int* __restrict__ srcE, int* __restrict__ bins) {
    int i = blockIdx.x * blockDim.x + threadIdx.x;
    if (i < E_TOTAL) atomicAdd(&bins[srcE[i]], 1);
}

// Single block, 1024 threads: exclusive scan of counts (in cursor) ->
// starts[0..NNODES] and cursor[v] = run start (scatter cursor).
__global__ void scan_kernel(int* __restrict__ cursor, int* __restrict__ starts) {
    __shared__ int s[1024];
    __shared__ int sbase;
    const int tid = threadIdx.x;
    if (tid == 0) sbase = 0;
    __syncthreads();
    const int NCH = (NNODES + 1023) / 1024;
    for (int c = 0; c < NCH; ++c) {
        const int i = c * 1024 + tid;
        const int x = (i < NNODES) ? cursor[i] : 0;
        s[tid] = x;
        __syncthreads();
        for (int off = 1; off < 1024; off <<= 1) {
            int t = (tid >= off) ? s[tid - off] : 0;
            __syncthreads();
            s[tid] += t;
            __syncthreads();
        }
        const int incl = s[tid];
        const int total = s[1023];
        const int b = sbase;
        if (i < NNODES) {
            starts[i] = b + incl - x;
            cursor[i] = b + incl - x;
        }
        __syncthreads();
        if (tid == 0) sbase = b + total;
        __syncthreads();
    }
    if (tid == 0) starts[NNODES] = sbase;
}

__global__ void scatter_kernel(const int* __restrict__ srcE, const int* __restrict__ dstE,
                               int* __restrict__ cursor, int2* __restrict__ sorted) {
    int i = blockIdx.x * blockDim.x + threadIdx.x;
    if (i >= E_TOTAL) return;
    int pos = atomicAdd(&cursor[srcE[i]], 1);
    int2 p; p.x = dstE[i]; p.y = i;
    sorted[pos] = p;
}

// ---------------- edge pass over sorted runs ----------------
// One 16-lane group per node v: us row held in regs across the whole run.
__global__ __launch_bounds__(256) void edge_score_sorted(
    const unsigned short* __restrict__ Us,
    const unsigned short* __restrict__ Ud,
    const int* __restrict__ starts,
    const int2* __restrict__ sorted,
    const float* __restrict__ w2,
    const float* __restrict__ b2p,
    float* __restrict__ out)
{
    const int gt = blockIdx.x * 256 + threadIdx.x;
    const int l = gt & 15;
    const int v = gt >> 4;
    if (v >= NNODES) return;

    float w2v[16];
#pragma unroll
    for (int j = 0; j < 16; ++j) w2v[j] = w2[l * 16 + j];
    const float b2 = *b2p;

    const int s0 = starts[v];
    const int s1 = starts[v + 1];
    if (s0 >= s1) return;

    const bf16x8* us = (const bf16x8*)(Us + (size_t)v * H + l * 16);
    const bf16x8 u0 = us[0], u1 = us[1];

    for (int base = s0; base < s1; base += 4) {
        int K = s1 - base; if (K > 4) K = 4;
        int2 p[4];
        bf16x8 vv[4][2];
#pragma unroll
        for (int k = 0; k < 4; ++k)
            if (k < K) p[k] = sorted[base + k];
#pragma unroll
        for (int k = 0; k < 4; ++k)
            if (k < K) {
                const bf16x8* ud = (const bf16x8*)(Ud + (size_t)p[k].x * H + l * 16);
                vv[k][0] = ud[0]; vv[k][1] = ud[1];
            }
#pragma unroll
        for (int k = 0; k < 4; ++k) {
            if (k >= K) break;
            float acc = 0.f;
#pragma unroll
            for (int j = 0; j < 8; ++j) {
                float hv = bf2f((unsigned short)u0[j]) + bf2f((unsigned short)vv[k][0][j]);
                acc = fmaf(fmaxf(hv, 0.f), w2v[j], acc);
            }
#pragma unroll
            for (int j = 0; j < 8; ++j) {
                float hv = bf2f((unsigned short)u1[j]) + bf2f((unsigned short)vv[k][1][j]);
                acc = fmaf(fmaxf(hv, 0.f), w2v[j + 8], acc);
            }
            acc += __shfl_xor(acc, 1, 16);
            acc += __shfl_xor(acc, 2, 16);
            acc += __shfl_xor(acc, 4, 16);
            acc += __shfl_xor(acc, 8, 16);
            if (l == 0) out[p[k].y] = acc + b2;
        }
    }
}

// ======================= R4 fallback (ws too small) ======================

#define TILE_M 32
#define NTILES (E_TOTAL / TILE_M)
#define GRID 2500

#if defined(__has_attribute)
#if __has_attribute(amdgpu_waves_per_eu)
#define LB __launch_bounds__(256) __attribute__((amdgpu_waves_per_eu(2, 2)))
#else
#define LB __launch_bounds__(256, 2)
#endif
#else
#define LB __launch_bounds__(256, 2)
#endif

__global__ void cvt_kernel(const float* __restrict__ h, const float* __restrict__ w1,
                           unsigned short* __restrict__ hbf, unsigned short* __restrict__ w1bf,
                           int n4h, int n4w) {
    int i = blockIdx.x * blockDim.x + threadIdx.x;
    const float* s; unsigned short* d; int j;
    if (i < n4h) { s = h; d = hbf; j = i; }
    else if (i < n4h + n4w) { s = w1; d = w1bf; j = i - n4h; }
    else return;
    float4 v = ((const float4*)s)[j];
    ushort4 o;
    o.x = f2bf(v.x); o.y = f2bf(v.y); o.z = f2bf(v.z); o.w = f2bf(v.w);
    ((ushort4*)d)[j] = o;
}

__global__ LB void edge_mlp(
    const unsigned short* __restrict__ hbf,
    const int* __restrict__ srcE,
    const int* __restrict__ dstE,
    const unsigned short* __restrict__ w1bf,
    const float* __restrict__ b1,
    const float* __restrict__ w2,
    const float* __restrict__ b2p,
    float* __restrict__ out)
{
    __shared__ __align__(16) unsigned short X[2][TILE_M * K2];
    __shared__ float red[2][TILE_M][5];

    const int tid = threadIdx.x;
    const int wave = tid >> 6;
    const int lane = tid & 63;
    const int lane15 = lane & 15;
    const int quad = lane >> 4;

    bf16x8 B[8][4];
#pragma unroll
    for (int kit = 0; kit < 8; ++kit)
#pragma unroll
        for (int nt = 0; nt < 4; ++nt) {
            int n = wave * 64 + nt * 16 + lane15;
            int k = kit * 32 + quad * 8;
            B[kit][nt] = *(const bf16x8*)(w1bf + n * K2 + k);
        }

    float b1v[4], w2v[4];
#pragma unroll
    for (int nt = 0; nt < 4; ++nt) {
        int n = wave * 64 + nt * 16 + lane15;
        b1v[nt] = b1[n];
        w2v[nt] = w2[n];
    }
    const float b2 = *b2p;

    const int r_off = tid >> 5;
    const int c = (tid & 31) ^ (r_off & 7);
    const int half = c >> 4;
    const int fc = c & 15;
    const int* idx_base = half ? dstE : srcE;
    const int gshort = fc * 8;

    const int t0 = blockIdx.x;
    int inode[4];

#pragma unroll
    for (int it = 0; it < 4; ++it)
        inode[it] = idx_base[t0 * TILE_M + it * 8 + r_off];
#pragma unroll
    for (int it = 0; it < 4; ++it)
        __builtin_amdgcn_global_load_lds(
            (gas_t)(hbf + inode[it] * D + gshort),
            (las_t)(&X[0][0] + it * 2048 + wave * 512), 16, 0, 0);
    {
        const int t1 = t0 + GRID;
#pragma unroll
        for (int it = 0; it < 4; ++it)
            inode[it] = idx_base[t1 * TILE_M + it * 8 + r_off];
    }

    int buf = 0;
    int prev_eb = -1;

    for (int tile = t0; tile < NTILES; tile += GRID) {
        __syncthreads();

        const int nt1 = tile + GRID;
        if (nt1 < NTILES) {
            unsigned short* Xn = &X[buf ^ 1][0];
#pragma unroll
            for (int it = 0; it < 4; ++it)
                __builtin_amdgcn_global_load_lds(
                    (gas_t)(hbf + inode[it] * D + gshort),
                    (las_t)(Xn + it * 2048 + wave * 512), 16, 0, 0);
        }
        const int nt2 = tile + 2 * GRID;
        if (nt2 < NTILES) {
            const int eb2 = nt2 * TILE_M;
#pragma unroll
            for (int it = 0; it < 4; ++it)
                inode[it] = idx_base[eb2 + it * 8 + r_off];
        }
        if (prev_eb >= 0 && tid < TILE_M) {
            float s = b2;
#pragma unroll
            for (int w = 0; w < 4; ++w) s += red[buf ^ 1][tid][w];
            out[prev_eb + tid] = s;
        }

        const unsigned short* Xc = &X[buf][0];
        f32x4 acc[2][4];
        const f32x4 zero = {0.f, 0.f, 0.f, 0.f};
#pragma unroll
        for (int ms = 0; ms < 2; ++ms)
#pragma unroll
            for (int nt = 0; nt < 4; ++nt)
                acc[ms][nt] = zero;

#pragma unroll
        for (int kit = 0; kit < 8; ++kit) {
            const int p8 = (((kit * 4 + quad) ^ (lane15 & 7))) * 8;
            bf16x8 a[2];
#pragma unroll
            for (int ms = 0; ms < 2; ++ms)
                a[ms] = *(const bf16x8*)&Xc[(ms * 16 + lane15) * K2 + p8];
#pragma unroll
            for (int ms = 0; ms < 2; ++ms)
#pragma unroll
                for (int nt = 0; nt < 4; ++nt)
                    acc[ms][nt] = __builtin_amdgcn_mfma_f32_16x16x32_bf16(
                        a[ms], B[kit][nt], acc[ms][nt], 0, 0, 0);
        }

#pragma unroll
        for (int ms = 0; ms < 2; ++ms)
#pragma unroll
            for (int r = 0; r < 4; ++r) {
                float p = 0.f;
#pragma unroll
                for (int nt = 0; nt < 4; ++nt) {
                    float hv = acc[ms][nt][r] + b1v[nt];
                    p = fmaf(fmaxf(hv, 0.f), w2v[nt], p);
                }
                p += __shfl_xor(p, 1, 16);
                p += __shfl_xor(p, 2, 16);
                p += __shfl_xor(p, 4, 16);
                p += __shfl_xor(p, 8, 16);
                if (lane15 == 0) red[buf][ms * 16 + quad * 4 + r][wave] = p;
            }
        prev_eb = tile * TILE_M;
        buf ^= 1;
    }

    __syncthreads();
    if (prev_eb >= 0 && tid < TILE_M) {
        float s = b2;
#pragma unroll
        for (int w = 0; w < 4; ++w) s += red[buf ^ 1][tid][w];
        out[prev_eb + tid] = s;
    }
}

// ================================ launch ================================

extern "C" void kernel_launch(void* const* d_in, const int* in_sizes, int n_in,
                              void* d_out, int out_size, void* d_ws, size_t ws_size,
                              hipStream_t stream) {
    const float* h    = (const float*)d_in[0];
    const int*   srcE = (const int*)d_in[1];
    const int*   dstE = (const int*)d_in[2];
    const float* W1   = (const float*)d_in[3];
    const float* b1   = (const float*)d_in[4];
    const float* w2   = (const float*)d_in[5];
    const float* b2   = (const float*)d_in[6];
    float* out = (float*)d_out;

    char* ws = (char*)d_ws;
    const size_t offUs     = 0;                       // 51,200,000 B
    const size_t offUd     = 51200000;                // 51,200,000 B
    const size_t offSorted = 102400000;               // 12,800,000 B (int2)
    const size_t offW1bf   = 115200000;               // 131,072 B
    const size_t offStarts = 115331072;               // 400,004 B -> pad
    const size_t offCursor = 115731080;               // 400,000 B
    const size_t need      = offCursor + 400000;      // ~116.1 MB

    if (ws_size >= need) {
        unsigned short* Us    = (unsigned short*)(ws + offUs);
        unsigned short* Ud    = (unsigned short*)(ws + offUd);
        int2*           sorted= (int2*)(ws + offSorted);
        unsigned short* w1bf  = (unsigned short*)(ws + offW1bf);
        int*            starts= (int*)(ws + offStarts);
        int*            cursor= (int*)(ws + offCursor);

        cvt_w1<<<(H * K2 / 4 + 255) / 256, 256, 0, stream>>>(W1, w1bf, H * K2 / 4);
        u_gemm<<<(NNODES + 63) / 64, 256, 0, stream>>>(h, w1bf, b1, Us, Ud);

        hipMemsetAsync(cursor, 0, NNODES * sizeof(int), stream);
        hist_kernel<<<(E_TOTAL + 255) / 256, 256, 0, stream>>>(srcE, cursor);
        scan_kernel<<<1, 1024, 0, stream>>>(cursor, starts);
        scatter_kernel<<<(E_TOTAL + 255) / 256, 256, 0, stream>>>(srcE, dstE, cursor, sorted);

        edge_score_sorted<<<(NNODES * 16 + 255) / 256, 256, 0, stream>>>(
            Us, Ud, starts, sorted, w2, b2, out);
    } else {
        unsigned short* hbf  = (unsigned short*)d_ws;
        unsigned short* w1bf = hbf + (size_t)NNODES * D;
        int n4h = NNODES * D / 4;
        int n4w = H * K2 / 4;
        int n4 = n4h + n4w;
        cvt_kernel<<<(n4 + 255) / 256, 256, 0, stream>>>(h, W1, hbf, w1bf, n4h, n4w);
        edge_mlp<<<GRID, 256, 0, stream>>>(hbf, srcE, dstE, w1bf, b1, w2, b2, out);
    }
}

// Round 8
// 369.899 us; speedup vs baseline: 1.8065x; 1.8065x over previous
//
#include <hip/hip_runtime.h>

// LinkPredictor: score[e] = w2 . relu(W1 . concat(h[src[e]], h[dst[e]]) + b1) + b2
// N_NODES=100000, N_EDGES=1600000, D=128, HIDDEN=256
//
// R8: consolidation. R7's counting-sort chain is structurally net-negative
// (scan 183 us single-block + hist/scatter ~160 us of device atomics, to save
// ~100 us of gather lines) -> dropped. Kept: R5/R6 factorization
// (Us = h.W1s^T + b1, Ud = h.W1d^T dense per node; edge pass = streaming
// gather+VALU, measured 222 us line-fill-capped) + R7's u_gemm bf16-W1
// fragment loads (kills ~4x line amplification of fp32 strided frag loads).

#define NNODES 100000
#define E_TOTAL 1600000
#define D 128
#define K2 256
#define H 256

typedef short bf16x8 __attribute__((ext_vector_type(8)));
typedef short bf16x4 __attribute__((ext_vector_type(4)));
typedef float f32x4 __attribute__((ext_vector_type(4)));
typedef const __attribute__((address_space(1))) unsigned short* gas_t;
typedef __attribute__((address_space(3))) unsigned short* las_t;

__device__ __forceinline__ unsigned short f2bf(float f) {
    unsigned u = __float_as_uint(f);
    u += 0x7fff + ((u >> 16) & 1);   // round-to-nearest-even
    return (unsigned short)(u >> 16);
}
__device__ __forceinline__ float bf2f(unsigned short s) {
    return __uint_as_float((unsigned)s << 16);
}

// ---------------- cvt W1 -> bf16 (128 KB, one-shot) ----------------
__global__ void cvt_w1(const float* __restrict__ W1, unsigned short* __restrict__ w1bf, int n4) {
    int i = blockIdx.x * blockDim.x + threadIdx.x;
    if (i >= n4) return;
    float4 v = ((const float4*)W1)[i];
    ushort4 o;
    o.x = f2bf(v.x); o.y = f2bf(v.y); o.z = f2bf(v.z); o.w = f2bf(v.w);
    ((ushort4*)w1bf)[i] = o;
}

// ---------------- u_gemm: per-node projections Us/Ud ----------------
// 64 node-rows/block, 4 waves x 64 cols, two K=128 halves. B-frags are bf16x8
// loads from w1bf (quads cover one 64B line per row -> no line amplification).
// C bounces through LDS S and drains as coalesced dwordx4.
__global__ __launch_bounds__(256, 2) void u_gemm(
    const float* __restrict__ h,
    const unsigned short* __restrict__ w1bf,
    const float* __restrict__ b1,
    unsigned short* __restrict__ Us,
    unsigned short* __restrict__ Ud)
{
    __shared__ __align__(16) unsigned short A[64 * 136];   // 17408 B
    __shared__ __align__(16) unsigned short S[64 * 268];   // 34304 B

    const int tid = threadIdx.x;
    const int wave = tid >> 6;
    const int lane = tid & 63;
    const int l15 = lane & 15;
    const int quad = lane >> 4;

    const int r0 = blockIdx.x * 64;
    int rows = NNODES - r0; if (rows > 64) rows = 64;

    const float4* hf4 = (const float4*)(h + (size_t)r0 * D);
    const int lim = rows * 32;
#pragma unroll
    for (int i = 0; i < 8; ++i) {
        int j = tid + i * 256;
        if (j < lim) {
            float4 v = hf4[j];
            bf16x4 b;
            b[0] = (short)f2bf(v.x); b[1] = (short)f2bf(v.y);
            b[2] = (short)f2bf(v.z); b[3] = (short)f2bf(v.w);
            *(bf16x4*)&A[(j >> 5) * 136 + (j & 31) * 4] = b;
        }
    }
    __syncthreads();

    for (int half = 0; half < 2; ++half) {
        const int koff = half * 128;
        unsigned short* U = half ? Ud : Us;

        bf16x8 B[4][4];
        float bias[4];
#pragma unroll
        for (int nt = 0; nt < 4; ++nt) {
            const int n = wave * 64 + nt * 16 + l15;
            bias[nt] = half ? 0.f : b1[n];
#pragma unroll
            for (int kit = 0; kit < 4; ++kit)
                B[kit][nt] = *(const bf16x8*)(w1bf + (size_t)n * K2 + koff + kit * 32 + quad * 8);
        }

        f32x4 acc[4][4];
        const f32x4 zero = {0.f, 0.f, 0.f, 0.f};
#pragma unroll
        for (int ms = 0; ms < 4; ++ms)
#pragma unroll
            for (int nt = 0; nt < 4; ++nt)
                acc[ms][nt] = zero;

#pragma unroll
        for (int kit = 0; kit < 4; ++kit) {
            bf16x8 a[4];
#pragma unroll
            for (int ms = 0; ms < 4; ++ms)
                a[ms] = *(const bf16x8*)&A[(ms * 16 + l15) * 136 + kit * 32 + quad * 8];
#pragma unroll
            for (int ms = 0; ms < 4; ++ms)
#pragma unroll
                for (int nt = 0; nt < 4; ++nt)
                    acc[ms][nt] = __builtin_amdgcn_mfma_f32_16x16x32_bf16(
                        a[ms], B[kit][nt], acc[ms][nt], 0, 0, 0);
        }

        if (half) __syncthreads();
#pragma unroll
        for (int ms = 0; ms < 4; ++ms)
#pragma unroll
            for (int r = 0; r < 4; ++r) {
                const int m = ms * 16 + quad * 4 + r;
#pragma unroll
                for (int nt = 0; nt < 4; ++nt)
                    S[m * 268 + wave * 64 + nt * 16 + l15] =
                        f2bf(acc[ms][nt][r] + bias[nt]);
            }
        __syncthreads();

#pragma unroll
        for (int i = 0; i < 8; ++i) {
            const int j = i * 256 + tid;
            const int row = j >> 5;
            const int cc = j & 31;
            if (row < rows) {
                bf16x8 vv = *(const bf16x8*)&S[row * 268 + cc * 8];
                *(bf16x8*)(U + (size_t)(r0 + row) * H + cc * 8) = vv;
            }
        }
    }
}

// ---------------- edge pass (R6, measured 222 us) ----------------
// 16-lane group processes 4 consecutive edges/iter; lane l covers hidden
// cols [16l,16l+16). 16 row-loads in flight per lane; float4 packed store.
__global__ __launch_bounds__(256) void edge_score(
    const unsigned short* __restrict__ Us,
    const unsigned short* __restrict__ Ud,
    const int* __restrict__ srcE,
    const int* __restrict__ dstE,
    const float* __restrict__ w2,
    const float* __restrict__ b2p,
    float* __restrict__ out)
{
    const int gt = blockIdx.x * 256 + threadIdx.x;
    const int l = gt & 15;
    const int q = gt >> 4;
    const int Q = (gridDim.x * 256) >> 4;
    const int NGRP = E_TOTAL / 4;   // 400000

    float w2v[16];
#pragma unroll
    for (int j = 0; j < 16; ++j) w2v[j] = w2[l * 16 + j];
    const float b2 = *b2p;

    for (int g = q; g < NGRP; g += Q) {
        const int e0 = g * 4;
        const int4 s4 = *(const int4*)(srcE + e0);
        const int4 d4 = *(const int4*)(dstE + e0);
        const int sv[4] = {s4.x, s4.y, s4.z, s4.w};
        const int dv[4] = {d4.x, d4.y, d4.z, d4.w};

        bf16x8 u[4][2], v[4][2];
#pragma unroll
        for (int k = 0; k < 4; ++k) {
            const bf16x8* us = (const bf16x8*)(Us + (size_t)sv[k] * H + l * 16);
            const bf16x8* ud = (const bf16x8*)(Ud + (size_t)dv[k] * H + l * 16);
            u[k][0] = us[0]; u[k][1] = us[1];
            v[k][0] = ud[0]; v[k][1] = ud[1];
        }

        float4 res;
        float* resp = (float*)&res;
#pragma unroll
        for (int k = 0; k < 4; ++k) {
            float acc = 0.f;
#pragma unroll
            for (int j = 0; j < 8; ++j) {
                float hv = bf2f((unsigned short)u[k][0][j]) + bf2f((unsigned short)v[k][0][j]);
                acc = fmaf(fmaxf(hv, 0.f), w2v[j], acc);
            }
#pragma unroll
            for (int j = 0; j < 8; ++j) {
                float hv = bf2f((unsigned short)u[k][1][j]) + bf2f((unsigned short)v[k][1][j]);
                acc = fmaf(fmaxf(hv, 0.f), w2v[j + 8], acc);
            }
            acc += __shfl_xor(acc, 1, 16);
            acc += __shfl_xor(acc, 2, 16);
            acc += __shfl_xor(acc, 4, 16);
            acc += __shfl_xor(acc, 8, 16);
            resp[k] = acc + b2;
        }
        if (l == 0) *(float4*)(out + e0) = res;
    }
}

// ======================= R4 fallback (ws too small) ======================

#define TILE_M 32
#define NTILES (E_TOTAL / TILE_M)
#define GRID 2500

#if defined(__has_attribute)
#if __has_attribute(amdgpu_waves_per_eu)
#define LB __launch_bounds__(256) __attribute__((amdgpu_waves_per_eu(2, 2)))
#else
#define LB __launch_bounds__(256, 2)
#endif
#else
#define LB __launch_bounds__(256, 2)
#endif

__global__ void cvt_kernel(const float* __restrict__ h, const float* __restrict__ w1,
                           unsigned short* __restrict__ hbf, unsigned short* __restrict__ w1bf,
                           int n4h, int n4w) {
    int i = blockIdx.x * blockDim.x + threadIdx.x;
    const float* s; unsigned short* d; int j;
    if (i < n4h) { s = h; d = hbf; j = i; }
    else if (i < n4h + n4w) { s = w1; d = w1bf; j = i - n4h; }
    else return;
    float4 v = ((const float4*)s)[j];
    ushort4 o;
    o.x = f2bf(v.x); o.y = f2bf(v.y); o.z = f2bf(v.z); o.w = f2bf(v.w);
    ((ushort4*)d)[j] = o;
}

__global__ LB void edge_mlp(
    const unsigned short* __restrict__ hbf,
    const int* __restrict__ srcE,
    const int* __restrict__ dstE,
    const unsigned short* __restrict__ w1bf,
    const float* __restrict__ b1,
    const float* __restrict__ w2,
    const float* __restrict__ b2p,
    float* __restrict__ out)
{
    __shared__ __align__(16) unsigned short X[2][TILE_M * K2];
    __shared__ float red[2][TILE_M][5];

    const int tid = threadIdx.x;
    const int wave = tid >> 6;
    const int lane = tid & 63;
    const int lane15 = lane & 15;
    const int quad = lane >> 4;

    bf16x8 B[8][4];
#pragma unroll
    for (int kit = 0; kit < 8; ++kit)
#pragma unroll
        for (int nt = 0; nt < 4; ++nt) {
            int n = wave * 64 + nt * 16 + lane15;
            int k = kit * 32 + quad * 8;
            B[kit][nt] = *(const bf16x8*)(w1bf + n * K2 + k);
        }

    float b1v[4], w2v[4];
#pragma unroll
    for (int nt = 0; nt < 4; ++nt) {
        int n = wave * 64 + nt * 16 + lane15;
        b1v[nt] = b1[n];
        w2v[nt] = w2[n];
    }
    const float b2 = *b2p;

    const int r_off = tid >> 5;
    const int c = (tid & 31) ^ (r_off & 7);
    const int half = c >> 4;
    const int fc = c & 15;
    const int* idx_base = half ? dstE : srcE;
    const int gshort = fc * 8;

    const int t0 = blockIdx.x;
    int inode[4];

#pragma unroll
    for (int it = 0; it < 4; ++it)
        inode[it] = idx_base[t0 * TILE_M + it * 8 + r_off];
#pragma unroll
    for (int it = 0; it < 4; ++it)
        __builtin_amdgcn_global_load_lds(
            (gas_t)(hbf + inode[it] * D + gshort),
            (las_t)(&X[0][0] + it * 2048 + wave * 512), 16, 0, 0);
    {
        const int t1 = t0 + GRID;
#pragma unroll
        for (int it = 0; it < 4; ++it)
            inode[it] = idx_base[t1 * TILE_M + it * 8 + r_off];
    }

    int buf = 0;
    int prev_eb = -1;

    for (int tile = t0; tile < NTILES; tile += GRID) {
        __syncthreads();

        const int nt1 = tile + GRID;
        if (nt1 < NTILES) {
            unsigned short* Xn = &X[buf ^ 1][0];
#pragma unroll
            for (int it = 0; it < 4; ++it)
                __builtin_amdgcn_global_load_lds(
                    (gas_t)(hbf + inode[it] * D + gshort),
                    (las_t)(Xn + it * 2048 + wave * 512), 16, 0, 0);
        }
        const int nt2 = tile + 2 * GRID;
        if (nt2 < NTILES) {
            const int eb2 = nt2 * TILE_M;
#pragma unroll
            for (int it = 0; it < 4; ++it)
                inode[it] = idx_base[eb2 + it * 8 + r_off];
        }
        if (prev_eb >= 0 && tid < TILE_M) {
            float s = b2;
#pragma unroll
            for (int w = 0; w < 4; ++w) s += red[buf ^ 1][tid][w];
            out[prev_eb + tid] = s;
        }

        const unsigned short* Xc = &X[buf][0];
        f32x4 acc[2][4];
        const f32x4 zero = {0.f, 0.f, 0.f, 0.f};
#pragma unroll
        for (int ms = 0; ms < 2; ++ms)
#pragma unroll
            for (int nt = 0; nt < 4; ++nt)
                acc[ms][nt] = zero;

#pragma unroll
        for (int kit = 0; kit < 8; ++kit) {
            const int p8 = (((kit * 4 + quad) ^ (lane15 & 7))) * 8;
            bf16x8 a[2];
#pragma unroll
            for (int ms = 0; ms < 2; ++ms)
                a[ms] = *(const bf16x8*)&Xc[(ms * 16 + lane15) * K2 + p8];
#pragma unroll
            for (int ms = 0; ms < 2; ++ms)
#pragma unroll
                for (int nt = 0; nt < 4; ++nt)
                    acc[ms][nt] = __builtin_amdgcn_mfma_f32_16x16x32_bf16(
                        a[ms], B[kit][nt], acc[ms][nt], 0, 0, 0);
        }

#pragma unroll
        for (int ms = 0; ms < 2; ++ms)
#pragma unroll
            for (int r = 0; r < 4; ++r) {
                float p = 0.f;
#pragma unroll
                for (int nt = 0; nt < 4; ++nt) {
                    float hv = acc[ms][nt][r] + b1v[nt];
                    p = fmaf(fmaxf(hv, 0.f), w2v[nt], p);
                }
                p += __shfl_xor(p, 1, 16);
                p += __shfl_xor(p, 2, 16);
                p += __shfl_xor(p, 4, 16);
                p += __shfl_xor(p, 8, 16);
                if (lane15 == 0) red[buf][ms * 16 + quad * 4 + r][wave] = p;
            }
        prev_eb = tile * TILE_M;
        buf ^= 1;
    }

    __syncthreads();
    if (prev_eb >= 0 && tid < TILE_M) {
        float s = b2;
#pragma unroll
        for (int w = 0; w < 4; ++w) s += red[buf ^ 1][tid][w];
        out[prev_eb + tid] = s;
    }
}

// ================================ launch ================================

extern "C" void kernel_launch(void* const* d_in, const int* in_sizes, int n_in,
                              void* d_out, int out_size, void* d_ws, size_t ws_size,
                              hipStream_t stream) {
    const float* h    = (const float*)d_in[0];
    const int*   srcE = (const int*)d_in[1];
    const int*   dstE = (const int*)d_in[2];
    const float* W1   = (const float*)d_in[3];
    const float* b1   = (const float*)d_in[4];
    const float* w2   = (const float*)d_in[5];
    const float* b2   = (const float*)d_in[6];
    float* out = (float*)d_out;

    char* ws = (char*)d_ws;
    const size_t offUs   = 0;                        // 51,200,000 B
    const size_t offUd   = 51200000;                 // 51,200,000 B
    const size_t offW1bf = 102400000;                // 131,072 B
    const size_t need    = offW1bf + 131072;         // ~102.53 MB (R7 proved ws >= 116.1 MB)

    if (ws_size >= need) {
        unsigned short* Us   = (unsigned short*)(ws + offUs);
        unsigned short* Ud   = (unsigned short*)(ws + offUd);
        unsigned short* w1bf = (unsigned short*)(ws + offW1bf);

        cvt_w1<<<(H * K2 / 4 + 255) / 256, 256, 0, stream>>>(W1, w1bf, H * K2 / 4);
        u_gemm<<<(NNODES + 63) / 64, 256, 0, stream>>>(h, w1bf, b1, Us, Ud);
        edge_score<<<4096, 256, 0, stream>>>(Us, Ud, srcE, dstE, w2, b2, out);
    } else {
        unsigned short* hbf  = (unsigned short*)d_ws;
        unsigned short* w1bf = hbf + (size_t)NNODES * D;
        int n4h = NNODES * D / 4;
        int n4w = H * K2 / 4;
        int n4 = n4h + n4w;
        cvt_kernel<<<(n4 + 255) / 256, 256, 0, stream>>>(h, W1, hbf, w1bf, n4h, n4w);
        edge_mlp<<<GRID, 256, 0, stream>>>(hbf, srcE, dstE, w1bf, b1, w2, b2, out);
    }
}